// Round 10
// baseline (476.194 us; speedup 1.0000x reference)
//
#include <hip/hip_runtime.h>

// MLA v3 forward, MI355X/gfx950. Round 10.
// Change vs round 9: attention rewritten on 32x32x16 MFMA (16 MAC per LDS
// byte vs 8 for 16x16x32) -> LDS-read traffic per MAC halves; 4 waves x
// 32 q-rows, QBLK=128, same grid/decode/staging. GEMMs unchanged.

typedef unsigned short u16;
typedef __attribute__((ext_vector_type(8))) short s16x8;
typedef __attribute__((ext_vector_type(4))) float f32x4;
typedef __attribute__((ext_vector_type(16))) float f32x16;
typedef __attribute__((ext_vector_type(8))) __bf16 bf16x8;
typedef __attribute__((ext_vector_type(4))) u16 u16x4;

#define S_LEN 2048
#define NH 16
#define HD 128
#define DQK 192
#define EMB 2048

#define GLOAD_LDS16(g, l)                                                      \
  __builtin_amdgcn_global_load_lds(                                            \
      (const __attribute__((address_space(1))) unsigned int*)(g),              \
      (__attribute__((address_space(3))) unsigned int*)(l), 16, 0, 0)

__device__ __forceinline__ u16 f2b(float f) {
  unsigned u = __builtin_bit_cast(unsigned, f);
  u += 0x7FFFu + ((u >> 16) & 1u);           // RNE to bf16
  return (u16)(u >> 16);
}
__device__ __forceinline__ float b2f(u16 v) {
  unsigned u = ((unsigned)v) << 16;
  return __builtin_bit_cast(float, u);
}
__device__ __forceinline__ bf16x8 ld_bf8(const u16* p) {
  return __builtin_bit_cast(bf16x8, *(const s16x8*)p);
}

__global__ __launch_bounds__(256) void f2b_kernel(const float* __restrict__ in,
                                                  u16* __restrict__ out, int n4) {
  int i = blockIdx.x * 256 + threadIdx.x;
  if (i >= n4) return;
  f32x4 v = *(const f32x4*)(in + (size_t)i * 4);
  u16x4 o = { f2b(v[0]), f2b(v[1]), f2b(v[2]), f2b(v[3]) };
  *(u16x4*)(out + (size_t)i * 4) = o;
}

// in: f32 [K][N] row-major -> out: bf16 [N][K] row-major. 64x64 tiles.
// Grid must be dim3(N/64, K/64).
__global__ __launch_bounds__(256) void transpose_f2b_kernel(const float* __restrict__ in,
                                                            u16* __restrict__ out,
                                                            int K, int N) {
  __shared__ u16 T[64 * 72];
  const int n0 = blockIdx.x * 64, k0 = blockIdx.y * 64;
  const int t = threadIdx.x;
#pragma unroll
  for (int r = 0; r < 4; ++r) {
    int kl = (t >> 4) + r * 16, nl = (t & 15) * 4;
    f32x4 v = *(const f32x4*)(in + (size_t)(k0 + kl) * N + n0 + nl);
#pragma unroll
    for (int j = 0; j < 4; ++j) T[(nl + j) * 72 + kl] = f2b(v[j]);
  }
  __syncthreads();
#pragma unroll
  for (int r = 0; r < 2; ++r) {
    int chunk = t + r * 256, nr = chunk >> 3, kc = (chunk & 7) * 8;
    *(s16x8*)(out + (size_t)(n0 + nr) * K + k0 + kc) = *(const s16x8*)(&T[nr * 72 + kc]);
  }
}

__global__ __launch_bounds__(256) void rope_table_kernel(float* __restrict__ cosT,
                                                         float* __restrict__ sinT) {
  int id = blockIdx.x * 256 + threadIdx.x;   // S_LEN*32
  int s = id >> 5, i = id & 31;
  float inv = exp2f(-(float)i * (13.287712379549449f / 32.0f));
  float ang = (float)s * inv;
  cosT[id] = cosf(ang);
  sinT[id] = sinf(ang);
}

// C = A[M,K](lda) @ BT[N,K]^T, bf16 in, fp32 accum. 128x128 tile, BK=64.
// LDS double-buffer, 1 barrier/iter; global_load_lds 16B, source-swizzled.
// MODE 0: bf16 [M,N]->Cout; MODE 1: fp32 [M,N]->Cout;
// MODE 4: col<2048 -> KCAT(Cout) [b,h,s,192]; col>=2048 -> VT(Cout2) [b,h,d,s];
// MODE 5: col<2048 -> QCAT(Cout) [b,h,s,192] scaled; col>=2048 -> QR(Cout2) [M,1024].
template<int MODE>
__global__ __launch_bounds__(256) void gemm_bt_kernel(const u16* __restrict__ A,
                                                      int lda,
                                                      const u16* __restrict__ BT,
                                                      void* __restrict__ Cout,
                                                      void* __restrict__ Cout2,
                                                      int M, int N, int K,
                                                      float scale) {
  __shared__ __align__(16) u16 As[2][128 * 64];
  __shared__ __align__(16) u16 Bs[2][128 * 64];
  const int t = threadIdx.x;
  const int lane = t & 63, wid = t >> 6;
  const int wr = (wid >> 1) * 64, wc = (wid & 1) * 64;
  const int bm0 = blockIdx.y * 128, bn0 = blockIdx.x * 128;
  const int lr = lane & 15, lg = lane >> 4;

  auto stage = [&](int k0, int buf) {
#pragma unroll
    for (int r = 0; r < 4; ++r) {            // 1024 chunks of 16B each for A and B
      int chunk = t + r * 256;
      int row = chunk >> 3, kcs = (chunk & 7) * 8;
      int kcg = kcs ^ ((row & 7) << 3);      // inverse swizzle on SOURCE
      GLOAD_LDS16(A + (size_t)(bm0 + row) * lda + k0 + kcg, &As[buf][chunk * 8]);
      GLOAD_LDS16(BT + (size_t)(bn0 + row) * K + k0 + kcg, &Bs[buf][chunk * 8]);
    }
  };

  f32x4 acc[4][4] = {};
  const int nt = K >> 6;
  stage(0, 0);
  for (int tk = 0; tk < nt; ++tk) {
    const int cur = tk & 1;
    __syncthreads();                         // stage(tk) complete; compute(tk-1) done
    if (tk + 1 < nt) stage((tk + 1) << 6, cur ^ 1);   // hides under compute(tk)
#pragma unroll
    for (int kk = 0; kk < 2; ++kk) {
      bf16x8 af[4], bfr[4];
      const int kbase = kk * 32 + lg * 8;
#pragma unroll
      for (int m = 0; m < 4; ++m) {
        int row = wr + m * 16 + lr;
        af[m] = ld_bf8(&As[cur][row * 64 + (kbase ^ ((row & 7) << 3))]);
      }
#pragma unroll
      for (int n = 0; n < 4; ++n) {
        int row = wc + n * 16 + lr;
        bfr[n] = ld_bf8(&Bs[cur][row * 64 + (kbase ^ ((row & 7) << 3))]);
      }
#pragma unroll
      for (int m = 0; m < 4; ++m)
#pragma unroll
        for (int n = 0; n < 4; ++n)
          acc[m][n] = __builtin_amdgcn_mfma_f32_16x16x32_bf16(af[m], bfr[n], acc[m][n], 0, 0, 0);
    }
  }

  // C/D layout: col = lane&15, row = (lane>>4)*4 + reg
#pragma unroll
  for (int m = 0; m < 4; ++m)
#pragma unroll
    for (int n = 0; n < 4; ++n)
#pragma unroll
      for (int rg = 0; rg < 4; ++rg) {
        int row = bm0 + wr + m * 16 + lg * 4 + rg;
        int col = bn0 + wc + n * 16 + lr;
        if (col >= N) continue;
        float v = acc[m][n][rg];
        if (MODE == 0) {
          ((u16*)Cout)[(size_t)row * N + col] = f2b(v * scale);
        } else if (MODE == 1) {
          ((float*)Cout)[(size_t)row * N + col] = v * scale;
        } else if (MODE == 4) {
          int bb = row >> 11, s = row & 2047;
          if (col < 2048) {
            int h = col >> 7, d = col & 127;
            ((u16*)Cout)[((size_t)(bb * NH + h) * S_LEN + s) * DQK + d] = f2b(v);
          } else {
            int c2 = col - 2048, h = c2 >> 7, d = c2 & 127;
            ((u16*)Cout2)[((size_t)(bb * NH + h) * HD + d) * S_LEN + s] = f2b(v);
          }
        } else {  // MODE 5
          int bb = row >> 11, s = row & 2047;
          if (col < 2048) {
            int h = col >> 7, d = col & 127;
            ((u16*)Cout)[((size_t)(bb * NH + h) * S_LEN + s) * DQK + d] = f2b(v * scale);
          } else {
            ((u16*)Cout2)[(size_t)row * 1024 + (col - 2048)] = f2b(v);
          }
        }
      }
}

// Fill rope halves of Qcat/Kcat. kr lives in CC cols 1024..1087 (stride 1088).
__global__ __launch_bounds__(256) void rope_assemble_kernel(const u16* __restrict__ qr,
                                                            const u16* __restrict__ cc,
                                                            const float* __restrict__ cosT,
                                                            const float* __restrict__ sinT,
                                                            u16* __restrict__ Qcat,
                                                            u16* __restrict__ Kcat) {
  int id = blockIdx.x * 256 + threadIdx.x;   // B*H*S*32 = 2^21
  int i = id & 31;
  int s = (id >> 5) & 2047;
  int h = (id >> 16) & 15;
  int b = id >> 20;
  float c = cosT[(s << 5) + i], sn = sinT[(s << 5) + i];
  const float SC = 0.07216878364870323f;     // 1/sqrt(192)

  size_t qbase = ((size_t)b * S_LEN + s) * 1024 + h * 64 + 2 * i;
  float qe = b2f(qr[qbase]), qo = b2f(qr[qbase + 1]);
  size_t obase = ((size_t)(b * NH + h) * S_LEN + s) * DQK + HD + 2 * i;
  Qcat[obase]     = f2b((qe * c - qo * sn) * SC);
  Qcat[obase + 1] = f2b((qe * sn + qo * c) * SC);

  size_t kbase = ((size_t)b * S_LEN + s) * 1088 + 1024 + 2 * i;
  float ke = b2f(cc[kbase]), ko = b2f(cc[kbase + 1]);
  Kcat[obase]     = f2b(ke * c - ko * sn);
  Kcat[obase + 1] = f2b(ke * sn + ko * c);
}

// Flash attention, causal, 32x32x16 MFMA. 4 waves x 32 q-rows (QBLK=128),
// kv tile 64. Grid 512: blocks n and n+256 land on the same CU with
// complementary q-tiles (qb, 15-qb) -> balanced.
// Fragment layouts (32x32x16): A row=lane&31, k=(lane>>5)*8+e;
// B col=lane&31, k=(lane>>5)*8+e; C col=lane&31,
// row=(reg&3)+8*(reg>>2)+4*(lane>>5).
__global__ __launch_bounds__(256, 2) void attn_kernel(const u16* __restrict__ Q,
                                                      const u16* __restrict__ K,
                                                      const u16* __restrict__ VT,
                                                      u16* __restrict__ O) {
  __shared__ u16 Ks[64 * 200];    // [kv][d0..191], stride 200 el (25 granules)
  __shared__ u16 Vs[128 * 72];    // [d][kv0..63], stride 72 el (9 granules)
  __shared__ u16 Ps[4 * 32 * 72]; // per-wave [q0..31][kv0..63], stride 72
  const int id = blockIdx.x;
  const int p8 = id >> 5, hb = id & 31;
  const int h = hb & 15, b = hb >> 4;
  const int qb = (p8 < 8) ? p8 : 23 - p8;
  const int q0 = qb * 128;
  const int t = threadIdx.x, lane = t & 63, wid = t >> 6;
  const int lc = lane & 31, hi = lane >> 5;
  const size_t qk_head = (size_t)(b * NH + h) * S_LEN * DQK;
  const size_t vt_head = (size_t)(b * NH + h) * HD * S_LEN;

  s16x8 kst[6], vst[4];
  auto gload = [&](int kt) {
#pragma unroll
    for (int r = 0; r < 6; ++r) {
      int chunk = t + r * 256, row = chunk / 24, cc = chunk % 24;
      kst[r] = *(const s16x8*)(K + qk_head + (size_t)(kt * 64 + row) * DQK + cc * 8);
    }
#pragma unroll
    for (int r = 0; r < 4; ++r) {
      int chunk = t + r * 256, d = chunk >> 3, cc = chunk & 7;
      vst[r] = *(const s16x8*)(VT + vt_head + (size_t)d * S_LEN + kt * 64 + cc * 8);
    }
  };
  auto swr = [&]() {
#pragma unroll
    for (int r = 0; r < 6; ++r) {
      int chunk = t + r * 256, row = chunk / 24, cc = chunk % 24;
      *(s16x8*)(&Ks[row * 200 + cc * 8]) = kst[r];
    }
#pragma unroll
    for (int r = 0; r < 4; ++r) {
      int chunk = t + r * 256, d = chunk >> 3, cc = chunk & 7;
      *(s16x8*)(&Vs[d * 72 + cc * 8]) = vst[r];
    }
  };

  // Q fragments: wave's 32 rows x 192, 12 k-steps of 16
  bf16x8 qa[12];
  {
    const u16* qrow = Q + qk_head + (size_t)(q0 + wid * 32 + lc) * DQK;
#pragma unroll
    for (int ks = 0; ks < 12; ++ks) qa[ks] = ld_bf8(qrow + ks * 16 + hi * 8);
  }

  f32x16 acc_o[4] = {};
  float m_r[16], l_r[16];
#pragma unroll
  for (int r = 0; r < 16; ++r) { m_r[r] = -INFINITY; l_r[r] = 0.f; }

  u16* psw = &Ps[wid * (32 * 72)];
  const int nt = 2 * qb + 2;
  gload(0);
#pragma unroll 1
  for (int kt = 0; kt < nt; ++kt) {
    __syncthreads();                 // all waves done reading previous tile
    swr();                           // stage tile kt
    if (kt + 1 < nt) gload(kt + 1);  // prefetch next
    __syncthreads();                 // tile kt visible

    // S = Q K^T : two 32x32 kv-blocks
    f32x16 sc[2];
#pragma unroll
    for (int cb = 0; cb < 2; ++cb) {
      f32x16 sv = {};
#pragma unroll
      for (int ks = 0; ks < 12; ++ks) {
        bf16x8 kb = ld_bf8(&Ks[(cb * 32 + lc) * 200 + ks * 16 + hi * 8]);
        sv = __builtin_amdgcn_mfma_f32_32x32x16_bf16(qa[ks], kb, sv, 0, 0, 0);
      }
      sc[cb] = sv;
    }

    if (kt >= 2 * qb) {              // diagonal tiles: causal mask
#pragma unroll
      for (int cb = 0; cb < 2; ++cb)
#pragma unroll
        for (int r = 0; r < 16; ++r) {
          int q_g = q0 + wid * 32 + (r & 3) + 8 * (r >> 2) + 4 * hi;
          int kv_g = kt * 64 + cb * 32 + lc;
          if (kv_g > q_g) sc[cb][r] = -INFINITY;
        }
    }

    // row max over 32 kv (lanes 0..31 of the 32-group; rows same per half)
    float pmax[16];
#pragma unroll
    for (int r = 0; r < 16; ++r) pmax[r] = fmaxf(sc[0][r], sc[1][r]);
#pragma unroll
    for (int off = 1; off < 32; off <<= 1)
#pragma unroll
      for (int r = 0; r < 16; ++r)
        pmax[r] = fmaxf(pmax[r], __shfl_xor(pmax[r], off, 64));

#pragma unroll
    for (int r = 0; r < 16; ++r) {
      float mn = fmaxf(m_r[r], pmax[r]);
      float alpha = __expf(m_r[r] - mn);
      m_r[r] = mn;
      l_r[r] *= alpha;
#pragma unroll
      for (int db = 0; db < 4; ++db) acc_o[db][r] *= alpha;
    }

    float ps[16];
#pragma unroll
    for (int r = 0; r < 16; ++r) ps[r] = 0.f;
#pragma unroll
    for (int cb = 0; cb < 2; ++cb)
#pragma unroll
      for (int r = 0; r < 16; ++r) {
        float pv = __expf(sc[cb][r] - m_r[r]);
        ps[r] += pv;
        int qrow = (r & 3) + 8 * (r >> 2) + 4 * hi;
        psw[qrow * 72 + cb * 32 + lc] = f2b(pv);
      }
#pragma unroll
    for (int off = 1; off < 32; off <<= 1)
#pragma unroll
      for (int r = 0; r < 16; ++r)
        ps[r] += __shfl_xor(ps[r], off, 64);
#pragma unroll
    for (int r = 0; r < 16; ++r) l_r[r] += ps[r];

    // PV: P (A-frag, row=q=lc, k=kv) x V (B-frag, col=d, k=kv)
    bf16x8 pa[4];
#pragma unroll
    for (int ks = 0; ks < 4; ++ks)
      pa[ks] = ld_bf8(&psw[lc * 72 + ks * 16 + hi * 8]);
#pragma unroll
    for (int db = 0; db < 4; ++db) {
#pragma unroll
      for (int ks = 0; ks < 4; ++ks) {
        bf16x8 vb = ld_bf8(&Vs[(db * 32 + lc) * 72 + ks * 16 + hi * 8]);
        acc_o[db] = __builtin_amdgcn_mfma_f32_32x32x16_bf16(pa[ks], vb, acc_o[db], 0, 0, 0);
      }
    }
  }

  // epilogue: O[b][s][h*128+d] bf16
  float rl[16];
#pragma unroll
  for (int r = 0; r < 16; ++r) rl[r] = 1.0f / l_r[r];
#pragma unroll
  for (int db = 0; db < 4; ++db)
#pragma unroll
    for (int r = 0; r < 16; ++r) {
      int s_glob = q0 + wid * 32 + (r & 3) + 8 * (r >> 2) + 4 * hi;
      int col = db * 32 + lc;
      O[((size_t)b * S_LEN + s_glob) * EMB + h * HD + col] = f2b(acc_o[db][r] * rl[r]);
    }
}

extern "C" void kernel_launch(void* const* d_in, const int* in_sizes, int n_in,
                              void* d_out, int out_size, void* d_ws, size_t ws_size,
                              hipStream_t stream) {
  const float* xf    = (const float*)d_in[0];
  const float* wckvf = (const float*)d_in[1];
  const float* wkf   = (const float*)d_in[2];
  const float* wvf   = (const float*)d_in[3];
  const float* wcqf  = (const float*)d_in[4];
  const float* wqf   = (const float*)d_in[5];
  const float* wqrf  = (const float*)d_in[6];
  const float* wkrf  = (const float*)d_in[7];
  const float* wof   = (const float*)d_in[8];
  (void)in_sizes; (void)n_in; (void)out_size; (void)ws_size;

  u16* ws = (u16*)d_ws;
  size_t off = 0;
  auto alloc = [&](size_t n) -> u16* { u16* p = ws + off; off += n; return p; };
  u16* XB     = alloc(8388608);   // x bf16 [4096,2048]
  // W1_T group [1088,2048]: wckv rows 0..511, wcq rows 512..1023, wkr rows 1024..1087
  u16* WCKV_T = alloc(1048576);   // [512,2048]
  u16* WCQ_T  = alloc(1048576);   // [512,2048]
  u16* WKR_T  = alloc(131072);    // [64,2048]
  // WKV_T group [4096,512]: wk rows 0..2047, wv rows 2048..4095
  u16* WK_T   = alloc(1048576);   // [2048,512]
  u16* WV_T   = alloc(1048576);   // [2048,512]
  // WQQR_T group [3072,512]: wq rows 0..2047, wqr rows 2048..3071
  u16* WQ_T   = alloc(1048576);   // [2048,512]
  u16* WQR_T  = alloc(524288);    // [1024,512]
  u16* WO_T   = alloc(4194304);   // [2048,2048]
  u16* CC     = alloc(4456448);   // [4096,1088]: ckv | cq | kr
  u16* QR     = alloc(4194304);   // [4096,1024]
  u16* QCAT   = alloc(12582912);  // [B,H,S,192]
  u16* KCAT   = alloc(12582912);
  u16* VT     = alloc(8388608);   // [B,H,128,S]
  u16* AOUT   = alloc(8388608);   // [4096,2048]
  float* COS_T = (float*)alloc(131072);
  float* SIN_T = (float*)alloc(131072);
  (void)WCQ_T; (void)WKR_T; (void)WV_T; (void)WQR_T;

  f2b_kernel<<<8192, 256, 0, stream>>>(xf, XB, 2097152);

  // transpose_f2b(in, out, K, N) with in = [K][N]; grid = dim3(N/64, K/64).
  transpose_f2b_kernel<<<dim3(8, 32),  256, 0, stream>>>(wckvf, WCKV_T, 2048, 512);
  transpose_f2b_kernel<<<dim3(8, 32),  256, 0, stream>>>(wcqf,  WCQ_T,  2048, 512);
  transpose_f2b_kernel<<<dim3(1, 32),  256, 0, stream>>>(wkrf,  WKR_T,  2048, 64);
  transpose_f2b_kernel<<<dim3(32, 8),  256, 0, stream>>>(wkf,   WK_T,   512, 2048);
  transpose_f2b_kernel<<<dim3(32, 8),  256, 0, stream>>>(wvf,   WV_T,   512, 2048);
  transpose_f2b_kernel<<<dim3(32, 8),  256, 0, stream>>>(wqf,   WQ_T,   512, 2048);
  transpose_f2b_kernel<<<dim3(16, 8),  256, 0, stream>>>(wqrf,  WQR_T,  512, 1024);
  transpose_f2b_kernel<<<dim3(32, 32), 256, 0, stream>>>(wof,   WO_T,   2048, 2048);

  rope_table_kernel<<<256, 256, 0, stream>>>(COS_T, SIN_T);

  const float SC = 0.07216878364870323f;  // 1/sqrt(192)
  // G1: x @ [w_ckv | w_cq | w_kr]  -> CC [4096,1088]
  gemm_bt_kernel<0><<<dim3(9, 32),  256, 0, stream>>>(XB, 2048, WCKV_T, CC, nullptr,
                                                      4096, 1088, 2048, 1.0f);
  // G2: c_kv @ [w_k | w_v] -> KCAT + VT
  gemm_bt_kernel<4><<<dim3(32, 32), 256, 0, stream>>>(CC, 1088, WK_T, KCAT, VT,
                                                      4096, 4096, 512, 1.0f);
  // G3: c_q @ [w_q | w_qr] -> QCAT(scaled) + QR
  gemm_bt_kernel<5><<<dim3(24, 32), 256, 0, stream>>>(CC + 512, 1088, WQ_T, QCAT, QR,
                                                      4096, 3072, 512, SC);

  rope_assemble_kernel<<<8192, 256, 0, stream>>>(QR, CC, COS_T, SIN_T, QCAT, KCAT);

  attn_kernel<<<512, 256, 0, stream>>>(QCAT, KCAT, VT, AOUT);

  // G4: attn_out @ w_o -> d_out (fp32)
  gemm_bt_kernel<1><<<dim3(16, 32), 256, 0, stream>>>(AOUT, 2048, WO_T, d_out, nullptr,
                                                      4096, 2048, 2048, 1.0f);
}

// Round 11
// 349.449 us; speedup vs baseline: 1.3627x; 1.3627x over previous
//
#include <hip/hip_runtime.h>

// MLA v3 forward, MI355X/gfx950. Round 11.
// Change vs round 10: attention keeps the (verified-correct) 32x32x16 MFMA
// math but stages K/V via double-buffered global_load_lds instead of
// register staging -> frees ~40 VGPRs (round 10 spilled: WRITE_SIZE 100MB).
// Linear LDS strides (192/64) with both-sides chunk XOR swizzle (rule #21).
// GEMMs and aux kernels identical to round 9.

typedef unsigned short u16;
typedef __attribute__((ext_vector_type(8))) short s16x8;
typedef __attribute__((ext_vector_type(4))) float f32x4;
typedef __attribute__((ext_vector_type(16))) float f32x16;
typedef __attribute__((ext_vector_type(8))) __bf16 bf16x8;
typedef __attribute__((ext_vector_type(4))) u16 u16x4;

#define S_LEN 2048
#define NH 16
#define HD 128
#define DQK 192
#define EMB 2048

#define GLOAD_LDS16(g, l)                                                      \
  __builtin_amdgcn_global_load_lds(                                            \
      (const __attribute__((address_space(1))) unsigned int*)(g),              \
      (__attribute__((address_space(3))) unsigned int*)(l), 16, 0, 0)

__device__ __forceinline__ u16 f2b(float f) {
  unsigned u = __builtin_bit_cast(unsigned, f);
  u += 0x7FFFu + ((u >> 16) & 1u);           // RNE to bf16
  return (u16)(u >> 16);
}
__device__ __forceinline__ float b2f(u16 v) {
  unsigned u = ((unsigned)v) << 16;
  return __builtin_bit_cast(float, u);
}
__device__ __forceinline__ bf16x8 ld_bf8(const u16* p) {
  return __builtin_bit_cast(bf16x8, *(const s16x8*)p);
}

__global__ __launch_bounds__(256) void f2b_kernel(const float* __restrict__ in,
                                                  u16* __restrict__ out, int n4) {
  int i = blockIdx.x * 256 + threadIdx.x;
  if (i >= n4) return;
  f32x4 v = *(const f32x4*)(in + (size_t)i * 4);
  u16x4 o = { f2b(v[0]), f2b(v[1]), f2b(v[2]), f2b(v[3]) };
  *(u16x4*)(out + (size_t)i * 4) = o;
}

// in: f32 [K][N] row-major -> out: bf16 [N][K] row-major. 64x64 tiles.
// Grid must be dim3(N/64, K/64).
__global__ __launch_bounds__(256) void transpose_f2b_kernel(const float* __restrict__ in,
                                                            u16* __restrict__ out,
                                                            int K, int N) {
  __shared__ u16 T[64 * 72];
  const int n0 = blockIdx.x * 64, k0 = blockIdx.y * 64;
  const int t = threadIdx.x;
#pragma unroll
  for (int r = 0; r < 4; ++r) {
    int kl = (t >> 4) + r * 16, nl = (t & 15) * 4;
    f32x4 v = *(const f32x4*)(in + (size_t)(k0 + kl) * N + n0 + nl);
#pragma unroll
    for (int j = 0; j < 4; ++j) T[(nl + j) * 72 + kl] = f2b(v[j]);
  }
  __syncthreads();
#pragma unroll
  for (int r = 0; r < 2; ++r) {
    int chunk = t + r * 256, nr = chunk >> 3, kc = (chunk & 7) * 8;
    *(s16x8*)(out + (size_t)(n0 + nr) * K + k0 + kc) = *(const s16x8*)(&T[nr * 72 + kc]);
  }
}

__global__ __launch_bounds__(256) void rope_table_kernel(float* __restrict__ cosT,
                                                         float* __restrict__ sinT) {
  int id = blockIdx.x * 256 + threadIdx.x;   // S_LEN*32
  int s = id >> 5, i = id & 31;
  float inv = exp2f(-(float)i * (13.287712379549449f / 32.0f));
  float ang = (float)s * inv;
  cosT[id] = cosf(ang);
  sinT[id] = sinf(ang);
}

// C = A[M,K](lda) @ BT[N,K]^T, bf16 in, fp32 accum. 128x128 tile, BK=64.
// LDS double-buffer, 1 barrier/iter; global_load_lds 16B, source-swizzled.
// MODE 0: bf16 [M,N]->Cout; MODE 1: fp32 [M,N]->Cout;
// MODE 4: col<2048 -> KCAT(Cout) [b,h,s,192]; col>=2048 -> VT(Cout2) [b,h,d,s];
// MODE 5: col<2048 -> QCAT(Cout) [b,h,s,192] scaled; col>=2048 -> QR(Cout2) [M,1024].
template<int MODE>
__global__ __launch_bounds__(256) void gemm_bt_kernel(const u16* __restrict__ A,
                                                      int lda,
                                                      const u16* __restrict__ BT,
                                                      void* __restrict__ Cout,
                                                      void* __restrict__ Cout2,
                                                      int M, int N, int K,
                                                      float scale) {
  __shared__ __align__(16) u16 As[2][128 * 64];
  __shared__ __align__(16) u16 Bs[2][128 * 64];
  const int t = threadIdx.x;
  const int lane = t & 63, wid = t >> 6;
  const int wr = (wid >> 1) * 64, wc = (wid & 1) * 64;
  const int bm0 = blockIdx.y * 128, bn0 = blockIdx.x * 128;
  const int lr = lane & 15, lg = lane >> 4;

  auto stage = [&](int k0, int buf) {
#pragma unroll
    for (int r = 0; r < 4; ++r) {            // 1024 chunks of 16B each for A and B
      int chunk = t + r * 256;
      int row = chunk >> 3, kcs = (chunk & 7) * 8;
      int kcg = kcs ^ ((row & 7) << 3);      // inverse swizzle on SOURCE
      GLOAD_LDS16(A + (size_t)(bm0 + row) * lda + k0 + kcg, &As[buf][chunk * 8]);
      GLOAD_LDS16(BT + (size_t)(bn0 + row) * K + k0 + kcg, &Bs[buf][chunk * 8]);
    }
  };

  f32x4 acc[4][4] = {};
  const int nt = K >> 6;
  stage(0, 0);
  for (int tk = 0; tk < nt; ++tk) {
    const int cur = tk & 1;
    __syncthreads();                         // stage(tk) complete; compute(tk-1) done
    if (tk + 1 < nt) stage((tk + 1) << 6, cur ^ 1);   // hides under compute(tk)
#pragma unroll
    for (int kk = 0; kk < 2; ++kk) {
      bf16x8 af[4], bfr[4];
      const int kbase = kk * 32 + lg * 8;
#pragma unroll
      for (int m = 0; m < 4; ++m) {
        int row = wr + m * 16 + lr;
        af[m] = ld_bf8(&As[cur][row * 64 + (kbase ^ ((row & 7) << 3))]);
      }
#pragma unroll
      for (int n = 0; n < 4; ++n) {
        int row = wc + n * 16 + lr;
        bfr[n] = ld_bf8(&Bs[cur][row * 64 + (kbase ^ ((row & 7) << 3))]);
      }
#pragma unroll
      for (int m = 0; m < 4; ++m)
#pragma unroll
        for (int n = 0; n < 4; ++n)
          acc[m][n] = __builtin_amdgcn_mfma_f32_16x16x32_bf16(af[m], bfr[n], acc[m][n], 0, 0, 0);
    }
  }

  // C/D layout: col = lane&15, row = (lane>>4)*4 + reg
#pragma unroll
  for (int m = 0; m < 4; ++m)
#pragma unroll
    for (int n = 0; n < 4; ++n)
#pragma unroll
      for (int rg = 0; rg < 4; ++rg) {
        int row = bm0 + wr + m * 16 + lg * 4 + rg;
        int col = bn0 + wc + n * 16 + lr;
        if (col >= N) continue;
        float v = acc[m][n][rg];
        if (MODE == 0) {
          ((u16*)Cout)[(size_t)row * N + col] = f2b(v * scale);
        } else if (MODE == 1) {
          ((float*)Cout)[(size_t)row * N + col] = v * scale;
        } else if (MODE == 4) {
          int bb = row >> 11, s = row & 2047;
          if (col < 2048) {
            int h = col >> 7, d = col & 127;
            ((u16*)Cout)[((size_t)(bb * NH + h) * S_LEN + s) * DQK + d] = f2b(v);
          } else {
            int c2 = col - 2048, h = c2 >> 7, d = c2 & 127;
            ((u16*)Cout2)[((size_t)(bb * NH + h) * HD + d) * S_LEN + s] = f2b(v);
          }
        } else {  // MODE 5
          int bb = row >> 11, s = row & 2047;
          if (col < 2048) {
            int h = col >> 7, d = col & 127;
            ((u16*)Cout)[((size_t)(bb * NH + h) * S_LEN + s) * DQK + d] = f2b(v * scale);
          } else {
            ((u16*)Cout2)[(size_t)row * 1024 + (col - 2048)] = f2b(v);
          }
        }
      }
}

// Fill rope halves of Qcat/Kcat. kr lives in CC cols 1024..1087 (stride 1088).
__global__ __launch_bounds__(256) void rope_assemble_kernel(const u16* __restrict__ qr,
                                                            const u16* __restrict__ cc,
                                                            const float* __restrict__ cosT,
                                                            const float* __restrict__ sinT,
                                                            u16* __restrict__ Qcat,
                                                            u16* __restrict__ Kcat) {
  int id = blockIdx.x * 256 + threadIdx.x;   // B*H*S*32 = 2^21
  int i = id & 31;
  int s = (id >> 5) & 2047;
  int h = (id >> 16) & 15;
  int b = id >> 20;
  float c = cosT[(s << 5) + i], sn = sinT[(s << 5) + i];
  const float SC = 0.07216878364870323f;     // 1/sqrt(192)

  size_t qbase = ((size_t)b * S_LEN + s) * 1024 + h * 64 + 2 * i;
  float qe = b2f(qr[qbase]), qo = b2f(qr[qbase + 1]);
  size_t obase = ((size_t)(b * NH + h) * S_LEN + s) * DQK + HD + 2 * i;
  Qcat[obase]     = f2b((qe * c - qo * sn) * SC);
  Qcat[obase + 1] = f2b((qe * sn + qo * c) * SC);

  size_t kbase = ((size_t)b * S_LEN + s) * 1088 + 1024 + 2 * i;
  float ke = b2f(cc[kbase]), ko = b2f(cc[kbase + 1]);
  Kcat[obase]     = f2b(ke * c - ko * sn);
  Kcat[obase + 1] = f2b(ke * sn + ko * c);
}

// Flash attention, causal, 32x32x16 MFMA. 4 waves x 32 q-rows (QBLK=128),
// kv tile 64. Grid 512 balanced (qb = p8<8 ? p8 : 23-p8).
// K/V staged via double-buffered global_load_lds into LINEAR LDS
// (stride 192 / 64 elements) with chunk swizzle cc ^= (row&7) applied on
// BOTH source and read (rule #21). Ps per-wave, stride 72 (round-10-proven).
// Fragment layouts (32x32x16, m74/m101): A row=lane&31, k=(lane>>5)*8+e;
// B col=lane&31, k=(lane>>5)*8+e; C col=lane&31, row=(r&3)+8*(r>>2)+4*(lane>>5).
__global__ __launch_bounds__(256) void attn_kernel(const u16* __restrict__ Q,
                                                   const u16* __restrict__ K,
                                                   const u16* __restrict__ VT,
                                                   u16* __restrict__ O) {
  __shared__ __align__(16) u16 Ks[2][64 * 192];   // linear [kv][d-chunks swz]
  __shared__ __align__(16) u16 Vs[2][128 * 64];   // linear [d][kv-chunks swz]
  __shared__ u16 Ps[4 * 32 * 72];                 // per-wave [q][kv], stride 72
  const int id = blockIdx.x;
  const int p8 = id >> 5, hb = id & 31;
  const int h = hb & 15, b = hb >> 4;
  const int qb = (p8 < 8) ? p8 : 23 - p8;
  const int q0 = qb * 128;
  const int t = threadIdx.x, lane = t & 63, wid = t >> 6;
  const int lc = lane & 31, hi = lane >> 5;
  const size_t qk_head = (size_t)(b * NH + h) * S_LEN * DQK;
  const size_t vt_head = (size_t)(b * NH + h) * HD * S_LEN;

  auto stage = [&](int kt, int buf) {
#pragma unroll
    for (int r = 0; r < 6; ++r) {        // K tile 64x192: 1536 16B chunks
      int c = t + r * 256, row = c / 24, cc = c % 24;
      int scc = cc ^ (row & 7);          // inverse swizzle on SOURCE
      GLOAD_LDS16(K + qk_head + (size_t)(kt * 64 + row) * DQK + scc * 8,
                  &Ks[buf][c * 8]);
    }
#pragma unroll
    for (int r = 0; r < 4; ++r) {        // V tile 128x64: 1024 16B chunks
      int c = t + r * 256, d = c >> 3, cc = c & 7;
      int scc = cc ^ (d & 7);
      GLOAD_LDS16(VT + vt_head + (size_t)d * S_LEN + kt * 64 + scc * 8,
                  &Vs[buf][c * 8]);
    }
  };

  // Q fragments: wave's 32 rows x 192, 12 k-steps of 16
  bf16x8 qa[12];
  {
    const u16* qrow = Q + qk_head + (size_t)(q0 + wid * 32 + lc) * DQK;
#pragma unroll
    for (int ks = 0; ks < 12; ++ks) qa[ks] = ld_bf8(qrow + ks * 16 + hi * 8);
  }

  f32x16 acc_o[4] = {};
  float m_r[16], l_r[16];
#pragma unroll
  for (int r = 0; r < 16; ++r) { m_r[r] = -INFINITY; l_r[r] = 0.f; }

  u16* psw = &Ps[wid * (32 * 72)];
  const int nt = 2 * qb + 2;
  stage(0, 0);
#pragma unroll 1
  for (int kt = 0; kt < nt; ++kt) {
    const int cur = kt & 1;
    __syncthreads();                     // stage(kt) landed; prev reads done
    if (kt + 1 < nt) stage(kt + 1, cur ^ 1);  // async, hides under compute

    // S = Q K^T : two 32x32 kv-blocks. Global chunk g=ks*2+hi at LDS chunk
    // g ^ (row&7); row = cb*32+lc so row&7 == lc&7.
    f32x16 sc[2];
#pragma unroll
    for (int cb = 0; cb < 2; ++cb) {
      f32x16 sv = {};
#pragma unroll
      for (int ks = 0; ks < 12; ++ks) {
        bf16x8 kb = ld_bf8(&Ks[cur][(cb * 32 + lc) * 192 +
                                    ((ks * 2 + hi) ^ (lc & 7)) * 8]);
        sv = __builtin_amdgcn_mfma_f32_32x32x16_bf16(qa[ks], kb, sv, 0, 0, 0);
      }
      sc[cb] = sv;
    }

    if (kt >= 2 * qb) {              // diagonal tiles: causal mask
#pragma unroll
      for (int cb = 0; cb < 2; ++cb)
#pragma unroll
        for (int r = 0; r < 16; ++r) {
          int q_g = q0 + wid * 32 + (r & 3) + 8 * (r >> 2) + 4 * hi;
          int kv_g = kt * 64 + cb * 32 + lc;
          if (kv_g > q_g) sc[cb][r] = -INFINITY;
        }
    }

    float pmax[16];
#pragma unroll
    for (int r = 0; r < 16; ++r) pmax[r] = fmaxf(sc[0][r], sc[1][r]);
#pragma unroll
    for (int off = 1; off < 32; off <<= 1)
#pragma unroll
      for (int r = 0; r < 16; ++r)
        pmax[r] = fmaxf(pmax[r], __shfl_xor(pmax[r], off, 64));

#pragma unroll
    for (int r = 0; r < 16; ++r) {
      float mn = fmaxf(m_r[r], pmax[r]);
      float alpha = __expf(m_r[r] - mn);
      m_r[r] = mn;
      l_r[r] *= alpha;
#pragma unroll
      for (int db = 0; db < 4; ++db) acc_o[db][r] *= alpha;
    }

    float ps[16];
#pragma unroll
    for (int r = 0; r < 16; ++r) ps[r] = 0.f;
#pragma unroll
    for (int cb = 0; cb < 2; ++cb)
#pragma unroll
      for (int r = 0; r < 16; ++r) {
        float pv = __expf(sc[cb][r] - m_r[r]);
        ps[r] += pv;
        int qrow = (r & 3) + 8 * (r >> 2) + 4 * hi;
        psw[qrow * 72 + cb * 32 + lc] = f2b(pv);
      }
#pragma unroll
    for (int off = 1; off < 32; off <<= 1)
#pragma unroll
      for (int r = 0; r < 16; ++r)
        ps[r] += __shfl_xor(ps[r], off, 64);
#pragma unroll
    for (int r = 0; r < 16; ++r) l_r[r] += ps[r];

    // PV: P (A-frag, row=q=lc, k=kv) x V (B-frag, col=d, k=kv)
    bf16x8 pa[4];
#pragma unroll
    for (int ks = 0; ks < 4; ++ks)
      pa[ks] = ld_bf8(&psw[lc * 72 + ks * 16 + hi * 8]);
#pragma unroll
    for (int db = 0; db < 4; ++db) {
#pragma unroll
      for (int ks = 0; ks < 4; ++ks) {
        bf16x8 vb = ld_bf8(&Vs[cur][(db * 32 + lc) * 64 +
                                    ((ks * 2 + hi) ^ (lc & 7)) * 8]);
        acc_o[db] = __builtin_amdgcn_mfma_f32_32x32x16_bf16(pa[ks], vb, acc_o[db], 0, 0, 0);
      }
    }
  }

  // epilogue: O[b][s][h*128+d] bf16
  float rl[16];
#pragma unroll
  for (int r = 0; r < 16; ++r) rl[r] = 1.0f / l_r[r];
#pragma unroll
  for (int db = 0; db < 4; ++db)
#pragma unroll
    for (int r = 0; r < 16; ++r) {
      int s_glob = q0 + wid * 32 + (r & 3) + 8 * (r >> 2) + 4 * hi;
      int col = db * 32 + lc;
      O[((size_t)b * S_LEN + s_glob) * EMB + h * HD + col] = f2b(acc_o[db][r] * rl[r]);
    }
}

extern "C" void kernel_launch(void* const* d_in, const int* in_sizes, int n_in,
                              void* d_out, int out_size, void* d_ws, size_t ws_size,
                              hipStream_t stream) {
  const float* xf    = (const float*)d_in[0];
  const float* wckvf = (const float*)d_in[1];
  const float* wkf   = (const float*)d_in[2];
  const float* wvf   = (const float*)d_in[3];
  const float* wcqf  = (const float*)d_in[4];
  const float* wqf   = (const float*)d_in[5];
  const float* wqrf  = (const float*)d_in[6];
  const float* wkrf  = (const float*)d_in[7];
  const float* wof   = (const float*)d_in[8];
  (void)in_sizes; (void)n_in; (void)out_size; (void)ws_size;

  u16* ws = (u16*)d_ws;
  size_t off = 0;
  auto alloc = [&](size_t n) -> u16* { u16* p = ws + off; off += n; return p; };
  u16* XB     = alloc(8388608);   // x bf16 [4096,2048]
  // W1_T group [1088,2048]: wckv rows 0..511, wcq rows 512..1023, wkr rows 1024..1087
  u16* WCKV_T = alloc(1048576);   // [512,2048]
  u16* WCQ_T  = alloc(1048576);   // [512,2048]
  u16* WKR_T  = alloc(131072);    // [64,2048]
  // WKV_T group [4096,512]: wk rows 0..2047, wv rows 2048..4095
  u16* WK_T   = alloc(1048576);   // [2048,512]
  u16* WV_T   = alloc(1048576);   // [2048,512]
  // WQQR_T group [3072,512]: wq rows 0..2047, wqr rows 2048..3071
  u16* WQ_T   = alloc(1048576);   // [2048,512]
  u16* WQR_T  = alloc(524288);    // [1024,512]
  u16* WO_T   = alloc(4194304);   // [2048,2048]
  u16* CC     = alloc(4456448);   // [4096,1088]: ckv | cq | kr
  u16* QR     = alloc(4194304);   // [4096,1024]
  u16* QCAT   = alloc(12582912);  // [B,H,S,192]
  u16* KCAT   = alloc(12582912);
  u16* VT     = alloc(8388608);   // [B,H,128,S]
  u16* AOUT   = alloc(8388608);   // [4096,2048]
  float* COS_T = (float*)alloc(131072);
  float* SIN_T = (float*)alloc(131072);
  (void)WCQ_T; (void)WKR_T; (void)WV_T; (void)WQR_T;

  f2b_kernel<<<8192, 256, 0, stream>>>(xf, XB, 2097152);

  // transpose_f2b(in, out, K, N) with in = [K][N]; grid = dim3(N/64, K/64).
  transpose_f2b_kernel<<<dim3(8, 32),  256, 0, stream>>>(wckvf, WCKV_T, 2048, 512);
  transpose_f2b_kernel<<<dim3(8, 32),  256, 0, stream>>>(wcqf,  WCQ_T,  2048, 512);
  transpose_f2b_kernel<<<dim3(1, 32),  256, 0, stream>>>(wkrf,  WKR_T,  2048, 64);
  transpose_f2b_kernel<<<dim3(32, 8),  256, 0, stream>>>(wkf,   WK_T,   512, 2048);
  transpose_f2b_kernel<<<dim3(32, 8),  256, 0, stream>>>(wvf,   WV_T,   512, 2048);
  transpose_f2b_kernel<<<dim3(32, 8),  256, 0, stream>>>(wqf,   WQ_T,   512, 2048);
  transpose_f2b_kernel<<<dim3(16, 8),  256, 0, stream>>>(wqrf,  WQR_T,  512, 1024);
  transpose_f2b_kernel<<<dim3(32, 32), 256, 0, stream>>>(wof,   WO_T,   2048, 2048);

  rope_table_kernel<<<256, 256, 0, stream>>>(COS_T, SIN_T);

  const float SC = 0.07216878364870323f;  // 1/sqrt(192)
  // G1: x @ [w_ckv | w_cq | w_kr]  -> CC [4096,1088]
  gemm_bt_kernel<0><<<dim3(9, 32),  256, 0, stream>>>(XB, 2048, WCKV_T, CC, nullptr,
                                                      4096, 1088, 2048, 1.0f);
  // G2: c_kv @ [w_k | w_v] -> KCAT + VT
  gemm_bt_kernel<4><<<dim3(32, 32), 256, 0, stream>>>(CC, 1088, WK_T, KCAT, VT,
                                                      4096, 4096, 512, 1.0f);
  // G3: c_q @ [w_q | w_qr] -> QCAT(scaled) + QR
  gemm_bt_kernel<5><<<dim3(24, 32), 256, 0, stream>>>(CC + 512, 1088, WQ_T, QCAT, QR,
                                                      4096, 3072, 512, SC);

  rope_assemble_kernel<<<8192, 256, 0, stream>>>(QR, CC, COS_T, SIN_T, QCAT, KCAT);

  attn_kernel<<<512, 256, 0, stream>>>(QCAT, KCAT, VT, AOUT);

  // G4: attn_out @ w_o -> d_out (fp32)
  gemm_bt_kernel<1><<<dim3(16, 32), 256, 0, stream>>>(AOUT, 2048, WO_T, d_out, nullptr,
                                                      4096, 2048, 2048, 1.0f);
}